// Round 5
// baseline (353.790 us; speedup 1.0000x reference)
//
#include <hip/hip_runtime.h>
#include <hip/hip_bf16.h>

#define N_NODES 6144
#define IN_F 256
#define N_HEADS 4
#define N_HID 64
#define NWORDS32 (N_NODES / 32)   // 192 u32 mask words per row

typedef __attribute__((ext_vector_type(8))) short short8;
typedef __attribute__((ext_vector_type(4))) float floatx4;
typedef _Float16 half2_t __attribute__((ext_vector_type(2)));
typedef _Float16 half8_t __attribute__((ext_vector_type(8)));

// ---------------- Kernel 0: pack adj int32 -> bitmask, 8x unrolled for MLP
__global__ __launch_bounds__(256) void pack_adj_kernel(
    const int* __restrict__ adj, unsigned long long* __restrict__ mask64, int nwords)
{
    const int wave = (blockIdx.x * 256 + threadIdx.x) >> 6;
    const int lane = threadIdx.x & 63;
    const int nwaves = (gridDim.x * 256) >> 6;
    for (int w = wave * 8; w + 7 < nwords; w += nwaves * 8) {
        int v[8];
        #pragma unroll
        for (int k = 0; k < 8; ++k) v[k] = adj[(size_t)(w + k) * 64 + lane];
        unsigned long long b[8];
        #pragma unroll
        for (int k = 0; k < 8; ++k) b[k] = __ballot(v[k] > 0);
        if (lane == 0) {
            #pragma unroll
            for (int k = 0; k < 8; ++k) mask64[w + k] = b[k];
        }
    }
}

// ---------------- Kernel 1: ht = h @ W (fp32); epilogue -> htF (f16 MFMA B-fragment layout),
//                  srcv (raw), tgtE1 = exp(tgt), tgtE2 = exp(0.2*tgt)
// htF flat F(head, jt, c, n, q, u) = ((((head*192 + jt)*4 + c)*16 + n)*4 + q)*8 + u
//   node j = jt*32 + q*8 + u, feature d = c*16 + n.
__global__ __launch_bounds__(256) void ht_gemm_kernel(
    const float* __restrict__ h, const float* __restrict__ W,
    const float* __restrict__ a, short* __restrict__ htF,
    float* __restrict__ srcv, float* __restrict__ tgtE1, float* __restrict__ tgtE2)
{
    __shared__ float As[32][34];   // [k][m], m 0..31 (even stride for aligned float2)
    __shared__ float Bs[32][68];   // [k][n], n 0..63
    __shared__ float redS[32][16];
    __shared__ float redT[32][16];

    const int head = blockIdx.y;
    const int i0 = blockIdx.x * 32;
    const int tid = threadIdx.x;
    const int tx = tid & 15, ty = tid >> 4;   // tx: 4-col group, ty: 2-row group

    float acc[2][4] = {};

    for (int k0 = 0; k0 < IN_F; k0 += 32) {
        __syncthreads();
        {   // h tile: 32 rows x 32 k = 256 float4s, one per thread
            const int m = tid >> 3, kq = tid & 7;
            const float4 v = *(const float4*)(h + (i0 + m) * IN_F + k0 + kq * 4);
            As[kq*4+0][m] = v.x; As[kq*4+1][m] = v.y;
            As[kq*4+2][m] = v.z; As[kq*4+3][m] = v.w;
        }
        #pragma unroll
        for (int it = 0; it < 2; ++it) {   // W tile: 32 k x 64 n = 512 float4s
            int l = it * 256 + tid;
            int k = l >> 4, nq = l & 15;
            *(float4*)&Bs[k][nq*4] = *(const float4*)(W + (k0 + k) * 256 + head * 64 + nq * 4);
        }
        __syncthreads();
        #pragma unroll
        for (int kk = 0; kk < 32; ++kk) {
            const float2 av = *(const float2*)&As[kk][ty*2];
            const float4 bv = *(const float4*)&Bs[kk][tx*4];
            const float aa[2] = {av.x, av.y};
            const float bb[4] = {bv.x, bv.y, bv.z, bv.w};
            #pragma unroll
            for (int r = 0; r < 2; ++r)
                #pragma unroll
                for (int c = 0; c < 4; ++c)
                    acc[r][c] = fmaf(aa[r], bb[c], acc[r][c]);
        }
    }

    // epilogue: scatter into f16 fragment-major layout
    #pragma unroll
    for (int r = 0; r < 2; ++r)
        #pragma unroll
        for (int c2 = 0; c2 < 4; ++c2) {
            const int d = tx * 4 + c2;
            const int j = i0 + ty * 2 + r;
            const int jt = j >> 5, q = (j >> 3) & 3, u = j & 7;
            const int c = d >> 4, n = d & 15;
            const size_t F = (((((size_t)head * 192 + jt) * 4 + c) * 16 + n) * 4 + q) * 8 + u;
            const _Float16 hv = (_Float16)acc[r][c2];   // RNE
            htF[F] = *(const short*)&hv;
        }

    float as_[4], at_[4];
    #pragma unroll
    for (int c = 0; c < 4; ++c) {
        as_[c] = a[head * 128 + tx * 4 + c];
        at_[c] = a[head * 128 + 64 + tx * 4 + c];
    }
    #pragma unroll
    for (int r = 0; r < 2; ++r) {
        float ps = 0.f, pt = 0.f;
        #pragma unroll
        for (int c = 0; c < 4; ++c) {
            ps = fmaf(acc[r][c], as_[c], ps);
            pt = fmaf(acc[r][c], at_[c], pt);
        }
        redS[ty*2+r][tx] = ps;
        redT[ty*2+r][tx] = pt;
    }
    __syncthreads();
    if (tid < 64) {
        const int row = tid & 31;
        const float* src = (tid < 32) ? &redS[row][0] : &redT[row][0];
        float s = 0.f;
        #pragma unroll
        for (int x = 0; x < 16; ++x) s += src[x];
        if (tid < 32) {
            srcv[head * N_NODES + i0 + row] = s;
        } else {
            tgtE1[head * N_NODES + i0 + row] = __expf(s);
            tgtE2[head * N_NODES + i0 + row] = __expf(0.2f * s);
        }
    }
}

// ---------------- Kernel 2: masked rank-1 softmax + PV via f16 MFMA (no exp in loop)
// grid = (384 i-tiles, JS j-chunks); block = (64,4): wave y = head y.
__global__ __launch_bounds__(256) void gat_main_kernel(
    const unsigned* __restrict__ mask32, const short* __restrict__ htF,
    const float* __restrict__ srcv, const float* __restrict__ tgtE1,
    const float* __restrict__ tgtE2,
    float* __restrict__ pnum, float* __restrict__ pden, int jlen)
{
    __shared__ unsigned smask[16][97];   // supports nw <= 96 (js >= 2)

    const int lane = threadIdx.x;   // 0..63
    const int head = threadIdx.y;   // 0..3
    const int jc = blockIdx.y;
    const int i0 = blockIdx.x * 16;
    const int m = lane & 15, quad = lane >> 4;
    const int row = i0 + m;
    const int jbase = jc * jlen;
    const int nw = jlen >> 5;

    const int tid = head * 64 + lane;
    for (int t = tid; t < 16 * nw; t += 256) {
        const int r = t / nw, w = t - r * nw;
        smask[r][w] = mask32[(size_t)(i0 + r) * NWORDS32 + (jbase >> 5) + w];
    }
    __syncthreads();

    const float sv = srcv[head * N_NODES + row];
    const float e1s = __expf(sv);
    const float e2s = __expf(0.2f * sv);
    const float* tE1 = tgtE1 + head * N_NODES;
    const float* tE2 = tgtE2 + head * N_NODES;
    const short* fb = htF + ((size_t)(head * 192 + (jbase >> 5)) * 4) * 512 + (m * 4 + quad) * 8;

    half8_t bones;
    #pragma unroll
    for (int u = 0; u < 8; ++u) bones[u] = (_Float16)1.0f;

    floatx4 acc0 = {0,0,0,0}, acc1 = {0,0,0,0}, acc2 = {0,0,0,0}, acc3 = {0,0,0,0};
    floatx4 accD = {0,0,0,0};

    for (int w = 0; w < nw; ++w) {
        const int jb = jbase + w * 32 + quad * 8;
        const unsigned bits = (smask[m][w] >> (quad * 8)) & 0xffu;
        const float4 p1a = *(const float4*)(tE1 + jb);
        const float4 p1b = *(const float4*)(tE1 + jb + 4);
        const float4 p2a = *(const float4*)(tE2 + jb);
        const float4 p2b = *(const float4*)(tE2 + jb + 4);
        const half8_t b0 = *(const half8_t*)(fb + (size_t)w * 2048);
        const half8_t b1 = *(const half8_t*)(fb + (size_t)w * 2048 + 512);
        const half8_t b2 = *(const half8_t*)(fb + (size_t)w * 2048 + 1024);
        const half8_t b3 = *(const half8_t*)(fb + (size_t)w * 2048 + 1536);

        const float E1[8] = {p1a.x, p1a.y, p1a.z, p1a.w, p1b.x, p1b.y, p1b.z, p1b.w};
        const float E2[8] = {p2a.x, p2a.y, p2a.z, p2a.w, p2b.x, p2b.y, p2b.z, p2b.w};

        float wv[8];
        #pragma unroll
        for (int u = 0; u < 8; ++u) {
            const float p1 = e1s * E1[u];                 // exp(s+t)
            float ww = (p1 >= 1.0f) ? p1 : e2s * E2[u];   // lrelu via factored exp
            wv[u] = (bits & (1u << u)) ? ww : 0.f;        // adjacency mask
        }
        half8_t af;
        #pragma unroll
        for (int u = 0; u < 4; ++u) {
            const half2_t p = __builtin_bit_cast(half2_t,
                __builtin_amdgcn_cvt_pkrtz(wv[2*u], wv[2*u+1]));
            af[2*u] = p[0]; af[2*u+1] = p[1];
        }

        acc0 = __builtin_amdgcn_mfma_f32_16x16x32_f16(af, b0, acc0, 0, 0, 0);
        acc1 = __builtin_amdgcn_mfma_f32_16x16x32_f16(af, b1, acc1, 0, 0, 0);
        acc2 = __builtin_amdgcn_mfma_f32_16x16x32_f16(af, b2, acc2, 0, 0, 0);
        acc3 = __builtin_amdgcn_mfma_f32_16x16x32_f16(af, b3, acc3, 0, 0, 0);
        accD = __builtin_amdgcn_mfma_f32_16x16x32_f16(af, bones, accD, 0, 0, 0);  // row sums -> den
    }

    const int slot = jc * N_HEADS + head;

    // den: every D column equals the row sum; lanes with m==0 hold col 0, rows quad*4+r
    if (m == 0) {
        #pragma unroll
        for (int r = 0; r < 4; ++r)
            pden[slot * N_NODES + i0 + quad * 4 + r] = accD[r];
    }

    // numerator partial: C/D layout col=lane&15, row=quad*4+r
    #pragma unroll
    for (int r = 0; r < 4; ++r) {
        const int gi = i0 + quad * 4 + r;
        float* np_ = pnum + ((size_t)slot * N_NODES + gi) * N_HID + m;
        np_[0]  = acc0[r];
        np_[16] = acc1[r];
        np_[32] = acc2[r];
        np_[48] = acc3[r];
    }
}

// ---------------- Kernel 3: reduce j-chunks, divide, mean over heads
__global__ __launch_bounds__(256) void finalize_kernel(
    const float* __restrict__ pnum, const float* __restrict__ pden,
    float* __restrict__ out, int js)
{
    const int idx = blockIdx.x * 256 + threadIdx.x;
    if (idx >= N_NODES * N_HID) return;
    const int i = idx >> 6;
    const int d = idx & 63;
    float s = 0.f;
    for (int hh = 0; hh < N_HEADS; ++hh) {
        float ns = 0.f, ds = 0.f;
        for (int jc = 0; jc < js; ++jc) {
            const int slot = jc * N_HEADS + hh;
            ns += pnum[((size_t)slot * N_NODES + i) * N_HID + d];
            ds += pden[slot * N_NODES + i];
        }
        s += ns / ds;
    }
    out[idx] = 0.25f * s;
}

extern "C" void kernel_launch(void* const* d_in, const int* in_sizes, int n_in,
                              void* d_out, int out_size, void* d_ws, size_t ws_size,
                              hipStream_t stream)
{
    const float* h   = (const float*)d_in[0];
    const int*   adj = (const int*)d_in[1];
    const float* W   = (const float*)d_in[2];
    const float* a   = (const float*)d_in[3];
    float* out = (float*)d_out;

    char* ws = (char*)d_ws;
    short* htF = (short*)ws;
    size_t off = (size_t)N_HEADS * N_HID * N_NODES * 2;             // 3,145,728
    float* srcv  = (float*)(ws + off);  off += (size_t)N_HEADS * N_NODES * 4;
    float* tgtE1 = (float*)(ws + off);  off += (size_t)N_HEADS * N_NODES * 4;
    float* tgtE2 = (float*)(ws + off);  off += (size_t)N_HEADS * N_NODES * 4;
    const int nwords64 = N_NODES * N_NODES / 64;                    // 589,824
    unsigned long long* mask64 = (unsigned long long*)(ws + off);
    off += (size_t)nwords64 * 8;

    const size_t per_js = (size_t)N_HEADS * N_NODES * N_HID * 4 + (size_t)N_HEADS * N_NODES * 4;
    int js = 8;                        // smask sized for js >= 2
    while (js > 2 && off + (size_t)js * per_js > ws_size) js >>= 1;
    const int jlen = N_NODES / js;

    float* pnum = (float*)(ws + off);  off += (size_t)js * N_HEADS * N_NODES * N_HID * 4;
    float* pden = (float*)(ws + off);

    pack_adj_kernel<<<2048, 256, 0, stream>>>(adj, mask64, nwords64);
    ht_gemm_kernel<<<dim3(N_NODES / 32, N_HEADS), 256, 0, stream>>>(h, W, a, htF, srcv, tgtE1, tgtE2);
    gat_main_kernel<<<dim3(N_NODES / 16, js), dim3(64, 4), 0, stream>>>(
        (const unsigned*)mask64, htF, srcv, tgtE1, tgtE2, pnum, pden, jlen);
    finalize_kernel<<<dim3((N_NODES * N_HID) / 256), 256, 0, stream>>>(pnum, pden, out, js);
}

// Round 6
// 315.578 us; speedup vs baseline: 1.1211x; 1.1211x over previous
//
#include <hip/hip_runtime.h>
#include <hip/hip_bf16.h>

#define N_NODES 6144
#define IN_F 256
#define N_HEADS 4
#define N_HID 64
#define JS 4
#define JLEN (N_NODES / JS)        // 1536
#define NW (JLEN / 32)             // 48
#define SMB_STRIDE 1544            // 1536 + 8: de-conflicts ds_read_b64 rows

typedef __attribute__((ext_vector_type(4))) float floatx4;
typedef _Float16 half2_t __attribute__((ext_vector_type(2)));
typedef _Float16 half8_t __attribute__((ext_vector_type(8)));
typedef __attribute__((ext_vector_type(4))) unsigned uint4_t;

// ---------------- Kernel 1: ht = h @ W (fp32); epilogue -> htF (f16 MFMA B-fragment layout),
//   srcv (f32), tE1pk/tE2pk = f16x2 pairs of exp(tgt), exp(0.2*tgt) over consecutive j.
// htF flat F(head, jt, c, n, q, u) = ((((head*192 + jt)*4 + c)*16 + n)*4 + q)*8 + u
//   node j = jt*32 + q*8 + u, feature d = c*16 + n.
__global__ __launch_bounds__(256) void ht_gemm_kernel(
    const float* __restrict__ h, const float* __restrict__ W,
    const float* __restrict__ a, short* __restrict__ htF,
    float* __restrict__ srcv, unsigned* __restrict__ tE1pk, unsigned* __restrict__ tE2pk)
{
    __shared__ float As[32][34];   // [k][m]
    __shared__ float Bs[32][68];   // [k][n]
    __shared__ float redS[32][16];
    __shared__ float redT[32][16];
    __shared__ unsigned short eh1[32], eh2[32];

    const int head = blockIdx.y;
    const int i0 = blockIdx.x * 32;
    const int tid = threadIdx.x;
    const int tx = tid & 15, ty = tid >> 4;

    float acc[2][4] = {};

    for (int k0 = 0; k0 < IN_F; k0 += 32) {
        __syncthreads();
        {   // h tile: 32 rows x 32 k
            const int m = tid >> 3, kq = tid & 7;
            const float4 v = *(const float4*)(h + (i0 + m) * IN_F + k0 + kq * 4);
            As[kq*4+0][m] = v.x; As[kq*4+1][m] = v.y;
            As[kq*4+2][m] = v.z; As[kq*4+3][m] = v.w;
        }
        #pragma unroll
        for (int it = 0; it < 2; ++it) {   // W tile: 32 k x 64 n
            int l = it * 256 + tid;
            int k = l >> 4, nq = l & 15;
            *(float4*)&Bs[k][nq*4] = *(const float4*)(W + (k0 + k) * 256 + head * 64 + nq * 4);
        }
        __syncthreads();
        #pragma unroll
        for (int kk = 0; kk < 32; ++kk) {
            const float2 av = *(const float2*)&As[kk][ty*2];
            const float4 bv = *(const float4*)&Bs[kk][tx*4];
            const float aa[2] = {av.x, av.y};
            const float bb[4] = {bv.x, bv.y, bv.z, bv.w};
            #pragma unroll
            for (int r = 0; r < 2; ++r)
                #pragma unroll
                for (int c = 0; c < 4; ++c)
                    acc[r][c] = fmaf(aa[r], bb[c], acc[r][c]);
        }
    }

    // epilogue: scatter into f16 fragment-major layout
    #pragma unroll
    for (int r = 0; r < 2; ++r)
        #pragma unroll
        for (int c2 = 0; c2 < 4; ++c2) {
            const int d = tx * 4 + c2;
            const int j = i0 + ty * 2 + r;
            const int jt = j >> 5, q = (j >> 3) & 3, u = j & 7;
            const int c = d >> 4, n = d & 15;
            const size_t F = (((((size_t)head * 192 + jt) * 4 + c) * 16 + n) * 4 + q) * 8 + u;
            const _Float16 hv = (_Float16)acc[r][c2];   // RNE
            htF[F] = *(const short*)&hv;
        }

    float as_[4], at_[4];
    #pragma unroll
    for (int c = 0; c < 4; ++c) {
        as_[c] = a[head * 128 + tx * 4 + c];
        at_[c] = a[head * 128 + 64 + tx * 4 + c];
    }
    #pragma unroll
    for (int r = 0; r < 2; ++r) {
        float ps = 0.f, pt = 0.f;
        #pragma unroll
        for (int c = 0; c < 4; ++c) {
            ps = fmaf(acc[r][c], as_[c], ps);
            pt = fmaf(acc[r][c], at_[c], pt);
        }
        redS[ty*2+r][tx] = ps;
        redT[ty*2+r][tx] = pt;
    }
    __syncthreads();
    if (tid < 64) {
        const int row = tid & 31;
        const float* src = (tid < 32) ? &redS[row][0] : &redT[row][0];
        float s = 0.f;
        #pragma unroll
        for (int x = 0; x < 16; ++x) s += src[x];
        if (tid < 32) {
            srcv[head * N_NODES + i0 + row] = s;
        } else {
            const _Float16 E1 = (_Float16)__expf(s);
            const _Float16 E2 = (_Float16)__expf(0.2f * s);
            eh1[row] = *(const unsigned short*)&E1;
            eh2[row] = *(const unsigned short*)&E2;
        }
    }
    __syncthreads();
    if (tid < 16) {
        const unsigned v1 = (unsigned)eh1[2*tid] | ((unsigned)eh1[2*tid+1] << 16);
        const unsigned v2 = (unsigned)eh2[2*tid] | ((unsigned)eh2[2*tid+1] << 16);
        tE1pk[head * (N_NODES/2) + i0/2 + tid] = v1;
        tE2pk[head * (N_NODES/2) + i0/2 + tid] = v2;
    }
}

// ---------------- Kernel 2: masked rank-1 softmax + PV via f16 MFMA
// w = max(e1s*E1, e2s*E2) (lrelu via monotone exp), mask via byte-mask perm+and.
// grid = (384 i-tiles, JS); block = (64,4): wave y = head y. adj staged int->byte in LDS.
__global__ __launch_bounds__(256) void gat_main_kernel(
    const int* __restrict__ adj, const short* __restrict__ htF,
    const float* __restrict__ srcv, const unsigned* __restrict__ tE1pk,
    const unsigned* __restrict__ tE2pk,
    float* __restrict__ pnum, float* __restrict__ pden)
{
    __shared__ unsigned char smaskB[16 * SMB_STRIDE];

    const int lane = threadIdx.x;   // 0..63
    const int head = threadIdx.y;   // 0..3
    const int jc = blockIdx.y;
    const int i0 = blockIdx.x * 16;
    const int m = lane & 15, quad = lane >> 4;
    const int row = i0 + m;
    const int jbase = jc * JLEN;

    // stage adj int32 -> byte mask (0x00/0xFF). adj values are {0,1}: byte = v*255.
    const int tid = head * 64 + lane;
    #pragma unroll
    for (int it = 0; it < 24; ++it) {            // 6144 int4s / 256 threads
        const int flat = it * 256 + tid;
        const int r = flat / 384;                // 384 int4 per 1536-col row
        const int c4 = flat - r * 384;
        const int4 v = *(const int4*)(adj + (size_t)(i0 + r) * N_NODES + jbase + c4 * 4);
        const unsigned b = (unsigned)(v.x | (v.y << 8) | (v.z << 16) | (v.w << 24)) * 255u;
        *(unsigned*)(smaskB + r * SMB_STRIDE + c4 * 4) = b;
    }
    __syncthreads();

    const float sv = srcv[head * N_NODES + row];
    const _Float16 e1h = (_Float16)__expf(sv);
    const _Float16 e2h = (_Float16)__expf(0.2f * sv);
    const half2_t e1s2 = {e1h, e1h};
    const half2_t e2s2 = {e2h, e2h};

    const unsigned* pe1 = tE1pk + head * (N_NODES/2) + (jbase >> 1);
    const unsigned* pe2 = tE2pk + head * (N_NODES/2) + (jbase >> 1);
    const short* fb = htF + ((size_t)(head * 192 + (jbase >> 5)) * 4) * 512 + (m * 4 + quad) * 8;

    half8_t bones;
    #pragma unroll
    for (int u = 0; u < 8; ++u) bones[u] = (_Float16)1.0f;

    floatx4 acc0 = {0,0,0,0}, acc1 = {0,0,0,0}, acc2 = {0,0,0,0}, acc3 = {0,0,0,0};
    floatx4 accD = {0,0,0,0};

    for (int w = 0; w < NW; ++w) {
        const uint4_t E1 = *(const uint4_t*)(pe1 + w * 16 + quad * 4);   // 4 f16x2 pairs
        const uint4_t E2 = *(const uint4_t*)(pe2 + w * 16 + quad * 4);
        const unsigned long long mB =
            *(const unsigned long long*)(smaskB + m * SMB_STRIDE + w * 32 + quad * 8);
        const unsigned mlo = (unsigned)mB, mhi = (unsigned)(mB >> 32);

        const half8_t b0 = *(const half8_t*)(fb + (size_t)w * 2048);
        const half8_t b1 = *(const half8_t*)(fb + (size_t)w * 2048 + 512);
        const half8_t b2 = *(const half8_t*)(fb + (size_t)w * 2048 + 1024);
        const half8_t b3 = *(const half8_t*)(fb + (size_t)w * 2048 + 1536);

        // expand mask bytes -> 16-bit halves: [b,b] per byte pair
        const unsigned k0 = __builtin_amdgcn_perm(0u, mlo, 0x01010000u);
        const unsigned k1 = __builtin_amdgcn_perm(0u, mlo, 0x03030202u);
        const unsigned k2 = __builtin_amdgcn_perm(0u, mhi, 0x01010000u);
        const unsigned k3 = __builtin_amdgcn_perm(0u, mhi, 0x03030202u);

        uint4_t af_u;
        #pragma unroll
        for (int p = 0; p < 4; ++p) {
            const unsigned e1u = (p == 0) ? E1.x : (p == 1) ? E1.y : (p == 2) ? E1.z : E1.w;
            const unsigned e2u = (p == 0) ? E2.x : (p == 1) ? E2.y : (p == 2) ? E2.z : E2.w;
            const unsigned ku  = (p == 0) ? k0 : (p == 1) ? k1 : (p == 2) ? k2 : k3;
            const half2_t p1 = __builtin_bit_cast(half2_t, e1u) * e1s2;   // v_pk_mul_f16
            const half2_t p2 = __builtin_bit_cast(half2_t, e2u) * e2s2;
            const half2_t mx = __builtin_elementwise_max(p1, p2);         // v_pk_max_f16
            const unsigned r = __builtin_bit_cast(unsigned, mx) & ku;     // mask -> +0.0
            if (p == 0) af_u.x = r; else if (p == 1) af_u.y = r;
            else if (p == 2) af_u.z = r; else af_u.w = r;
        }
        const half8_t af = __builtin_bit_cast(half8_t, af_u);

        acc0 = __builtin_amdgcn_mfma_f32_16x16x32_f16(af, b0, acc0, 0, 0, 0);
        acc1 = __builtin_amdgcn_mfma_f32_16x16x32_f16(af, b1, acc1, 0, 0, 0);
        acc2 = __builtin_amdgcn_mfma_f32_16x16x32_f16(af, b2, acc2, 0, 0, 0);
        acc3 = __builtin_amdgcn_mfma_f32_16x16x32_f16(af, b3, acc3, 0, 0, 0);
        accD = __builtin_amdgcn_mfma_f32_16x16x32_f16(af, bones, accD, 0, 0, 0);  // den
    }

    const int slot = jc * N_HEADS + head;

    if (m == 0) {
        #pragma unroll
        for (int r = 0; r < 4; ++r)
            pden[slot * N_NODES + i0 + quad * 4 + r] = accD[r];
    }

    #pragma unroll
    for (int r = 0; r < 4; ++r) {
        const int gi = i0 + quad * 4 + r;
        float* np_ = pnum + ((size_t)slot * N_NODES + gi) * N_HID + m;
        np_[0]  = acc0[r];
        np_[16] = acc1[r];
        np_[32] = acc2[r];
        np_[48] = acc3[r];
    }
}

// ---------------- Kernel 3: reduce j-chunks, divide, mean over heads
__global__ __launch_bounds__(256) void finalize_kernel(
    const float* __restrict__ pnum, const float* __restrict__ pden,
    float* __restrict__ out)
{
    const int idx = blockIdx.x * 256 + threadIdx.x;
    if (idx >= N_NODES * N_HID) return;
    const int i = idx >> 6;
    const int d = idx & 63;
    float s = 0.f;
    for (int hh = 0; hh < N_HEADS; ++hh) {
        float ns = 0.f, ds = 0.f;
        #pragma unroll
        for (int jc = 0; jc < JS; ++jc) {
            const int slot = jc * N_HEADS + hh;
            ns += pnum[((size_t)slot * N_NODES + i) * N_HID + d];
            ds += pden[slot * N_NODES + i];
        }
        s += ns / ds;
    }
    out[idx] = 0.25f * s;
}

extern "C" void kernel_launch(void* const* d_in, const int* in_sizes, int n_in,
                              void* d_out, int out_size, void* d_ws, size_t ws_size,
                              hipStream_t stream)
{
    const float* h   = (const float*)d_in[0];
    const int*   adj = (const int*)d_in[1];
    const float* W   = (const float*)d_in[2];
    const float* a   = (const float*)d_in[3];
    float* out = (float*)d_out;

    char* ws = (char*)d_ws;
    // htF 3.1MB | srcv 98KB | tE1pk 49KB | tE2pk 49KB | pnum 25.2MB | pden 0.4MB  (~29MB)
    short* htF = (short*)ws;
    size_t off = (size_t)N_HEADS * N_HID * N_NODES * 2;
    float* srcv = (float*)(ws + off);       off += (size_t)N_HEADS * N_NODES * 4;
    unsigned* tE1pk = (unsigned*)(ws + off); off += (size_t)N_HEADS * (N_NODES/2) * 4;
    unsigned* tE2pk = (unsigned*)(ws + off); off += (size_t)N_HEADS * (N_NODES/2) * 4;
    float* pnum = (float*)(ws + off);        off += (size_t)JS * N_HEADS * N_NODES * N_HID * 4;
    float* pden = (float*)(ws + off);

    ht_gemm_kernel<<<dim3(N_NODES / 32, N_HEADS), 256, 0, stream>>>(h, W, a, htF, srcv, tE1pk, tE2pk);
    gat_main_kernel<<<dim3(N_NODES / 16, JS), dim3(64, 4), 0, stream>>>(
        adj, htF, srcv, tE1pk, tE2pk, pnum, pden);
    finalize_kernel<<<dim3((N_NODES * N_HID) / 256), 256, 0, stream>>>(pnum, pden, out);
}

// Round 7
// 282.847 us; speedup vs baseline: 1.2508x; 1.1157x over previous
//
#include <hip/hip_runtime.h>
#include <hip/hip_bf16.h>

#define N_NODES 6144
#define IN_F 256
#define N_HEADS 4
#define N_HID 64
#define NWORDS (N_NODES / 32)      // 192 u32 mask words per full row

typedef __attribute__((ext_vector_type(4))) float floatx4;
typedef _Float16 half2_t __attribute__((ext_vector_type(2)));
typedef _Float16 half8_t __attribute__((ext_vector_type(8)));
typedef __attribute__((ext_vector_type(4))) unsigned uint4_t;
typedef short short2v __attribute__((ext_vector_type(2)));

// ---------------- Kernel 0: pack adj int32 -> bit mask, lane-independent (no ballot).
// Each lane builds one u32 word from 32 consecutive ints; wave reads 8KB contiguous.
__global__ __launch_bounds__(256) void pack_adj_kernel(
    const int* __restrict__ adj, unsigned* __restrict__ mask32)
{
    const int waveId = (blockIdx.x * 256 + threadIdx.x) >> 6;   // 0..6143
    const int lane = threadIdx.x & 63;
    #pragma unroll
    for (int c = 0; c < 3; ++c) {
        const size_t W = ((size_t)c * 6144 + waveId) * 64 + lane;
        const int* p = adj + W * 32;
        unsigned mw = 0;
        #pragma unroll
        for (int k = 0; k < 8; ++k) {
            const int4 v = *(const int4*)(p + k * 4);           // adj values are {0,1}
            mw |= (unsigned)v.x << (k * 4 + 0);
            mw |= (unsigned)v.y << (k * 4 + 1);
            mw |= (unsigned)v.z << (k * 4 + 2);
            mw |= (unsigned)v.w << (k * 4 + 3);
        }
        mask32[W] = mw;
    }
}

// ---------------- Kernel 1: ht = h @ W (fp32); epilogue -> htF (f16 MFMA B-fragment layout),
//   srcv (f32), tE1pk/tE2pk = f16x2 pairs of exp(tgt), exp(0.2*tgt).
// htF flat F(head, jt, c, n, q, u) = ((((head*192 + jt)*4 + c)*16 + n)*4 + q)*8 + u
__global__ __launch_bounds__(256) void ht_gemm_kernel(
    const float* __restrict__ h, const float* __restrict__ W,
    const float* __restrict__ a, short* __restrict__ htF,
    float* __restrict__ srcv, unsigned* __restrict__ tE1pk, unsigned* __restrict__ tE2pk)
{
    __shared__ float As[32][34];
    __shared__ float Bs[32][68];
    __shared__ float redS[32][16];
    __shared__ float redT[32][16];
    __shared__ unsigned short eh1[32], eh2[32];

    const int head = blockIdx.y;
    const int i0 = blockIdx.x * 32;
    const int tid = threadIdx.x;
    const int tx = tid & 15, ty = tid >> 4;

    float acc[2][4] = {};

    for (int k0 = 0; k0 < IN_F; k0 += 32) {
        __syncthreads();
        {
            const int m = tid >> 3, kq = tid & 7;
            const float4 v = *(const float4*)(h + (i0 + m) * IN_F + k0 + kq * 4);
            As[kq*4+0][m] = v.x; As[kq*4+1][m] = v.y;
            As[kq*4+2][m] = v.z; As[kq*4+3][m] = v.w;
        }
        #pragma unroll
        for (int it = 0; it < 2; ++it) {
            int l = it * 256 + tid;
            int k = l >> 4, nq = l & 15;
            *(float4*)&Bs[k][nq*4] = *(const float4*)(W + (k0 + k) * 256 + head * 64 + nq * 4);
        }
        __syncthreads();
        #pragma unroll
        for (int kk = 0; kk < 32; ++kk) {
            const float2 av = *(const float2*)&As[kk][ty*2];
            const float4 bv = *(const float4*)&Bs[kk][tx*4];
            const float aa[2] = {av.x, av.y};
            const float bb[4] = {bv.x, bv.y, bv.z, bv.w};
            #pragma unroll
            for (int r = 0; r < 2; ++r)
                #pragma unroll
                for (int c = 0; c < 4; ++c)
                    acc[r][c] = fmaf(aa[r], bb[c], acc[r][c]);
        }
    }

    #pragma unroll
    for (int r = 0; r < 2; ++r)
        #pragma unroll
        for (int c2 = 0; c2 < 4; ++c2) {
            const int d = tx * 4 + c2;
            const int j = i0 + ty * 2 + r;
            const int jt = j >> 5, q = (j >> 3) & 3, u = j & 7;
            const int c = d >> 4, n = d & 15;
            const size_t F = (((((size_t)head * 192 + jt) * 4 + c) * 16 + n) * 4 + q) * 8 + u;
            const _Float16 hv = (_Float16)acc[r][c2];
            htF[F] = *(const short*)&hv;
        }

    float as_[4], at_[4];
    #pragma unroll
    for (int c = 0; c < 4; ++c) {
        as_[c] = a[head * 128 + tx * 4 + c];
        at_[c] = a[head * 128 + 64 + tx * 4 + c];
    }
    #pragma unroll
    for (int r = 0; r < 2; ++r) {
        float ps = 0.f, pt = 0.f;
        #pragma unroll
        for (int c = 0; c < 4; ++c) {
            ps = fmaf(acc[r][c], as_[c], ps);
            pt = fmaf(acc[r][c], at_[c], pt);
        }
        redS[ty*2+r][tx] = ps;
        redT[ty*2+r][tx] = pt;
    }
    __syncthreads();
    if (tid < 64) {
        const int row = tid & 31;
        const float* src = (tid < 32) ? &redS[row][0] : &redT[row][0];
        float s = 0.f;
        #pragma unroll
        for (int x = 0; x < 16; ++x) s += src[x];
        if (tid < 32) {
            srcv[head * N_NODES + i0 + row] = s;
        } else {
            const _Float16 E1 = (_Float16)__expf(s);
            const _Float16 E2 = (_Float16)__expf(0.2f * s);
            eh1[row] = *(const unsigned short*)&E1;
            eh2[row] = *(const unsigned short*)&E2;
        }
    }
    __syncthreads();
    if (tid < 16) {
        const unsigned v1 = (unsigned)eh1[2*tid] | ((unsigned)eh1[2*tid+1] << 16);
        const unsigned v2 = (unsigned)eh2[2*tid] | ((unsigned)eh2[2*tid+1] << 16);
        tE1pk[head * (N_NODES/2) + i0/2 + tid] = v1;
        tE2pk[head * (N_NODES/2) + i0/2 + tid] = v2;
    }
}

// ---------------- Kernel 2: 64 i-rows per wave (4 MFMA row-tiles) -> 2 B issued/element.
// grid = (24 row-groups, js, 4 heads); block = (64,4): wave wy takes rows rb0+wy*64..+63.
// All 4 waves share one head -> b-fragment loads L1-shared.
__global__ __launch_bounds__(256, 3) void gat_main_kernel(
    const unsigned* __restrict__ mask32, const short* __restrict__ htF,
    const float* __restrict__ srcv, const unsigned* __restrict__ tE1pk,
    const unsigned* __restrict__ tE2pk,
    float* __restrict__ pnum, float* __restrict__ pden, int nw)
{
    __shared__ unsigned smask[256 * 49];   // 256 rows x up to 48 words, stride 49 (coprime w/ 32)

    const int lane = threadIdx.x;
    const int wy = threadIdx.y;
    const int jc = blockIdx.y;
    const int head = blockIdx.z;
    const int rb0 = blockIdx.x * 256;
    const int m = lane & 15, quad = lane >> 4;
    const int jbase = jc * nw * 32;

    // stage packed mask: 256 rows x nw words
    const int tid = wy * 64 + lane;
    const int perThread = nw >> 2;              // int4s per thread (6 or 12)
    for (int it = 0; it < perThread; ++it) {
        const int flat = it * 256 + tid;
        const int r = flat / perThread, w4 = flat % perThread;
        const uint4_t v = *(const uint4_t*)(mask32 + (size_t)(rb0 + r) * NWORDS + jc * nw + w4 * 4);
        unsigned* dst = &smask[r * 49 + w4 * 4];
        dst[0] = v.x; dst[1] = v.y; dst[2] = v.z; dst[3] = v.w;
    }
    __syncthreads();

    const int rowbase = rb0 + wy * 64;
    half2_t e1s[4], e2s[4];
    #pragma unroll
    for (int t = 0; t < 4; ++t) {
        const float sv = srcv[head * N_NODES + rowbase + t * 16 + m];
        const _Float16 a1 = (_Float16)__expf(sv);
        const _Float16 a2 = (_Float16)__expf(0.2f * sv);
        e1s[t] = (half2_t){a1, a1};
        e2s[t] = (half2_t){a2, a2};
    }

    const unsigned* pe1 = tE1pk + head * (N_NODES/2) + (jbase >> 1);
    const unsigned* pe2 = tE2pk + head * (N_NODES/2) + (jbase >> 1);
    const short* fb = htF + ((size_t)(head * 192 + (jbase >> 5)) * 4) * 512 + (m * 4 + quad) * 8;
    const unsigned* mrow = &smask[(wy * 64 + m) * 49];   // tile t adds t*16*49

    half8_t bones;
    #pragma unroll
    for (int u = 0; u < 8; ++u) bones[u] = (_Float16)1.0f;

    floatx4 accN[4][4];
    floatx4 accD[4];
    #pragma unroll
    for (int t = 0; t < 4; ++t) {
        accD[t] = (floatx4){0,0,0,0};
        #pragma unroll
        for (int c = 0; c < 4; ++c) accN[t][c] = (floatx4){0,0,0,0};
    }

    for (int w = 0; w < nw; ++w) {
        const uint4_t E1 = *(const uint4_t*)(pe1 + w * 16 + quad * 4);
        const uint4_t E2 = *(const uint4_t*)(pe2 + w * 16 + quad * 4);
        const unsigned E1a[4] = {E1.x, E1.y, E1.z, E1.w};
        const unsigned E2a[4] = {E2.x, E2.y, E2.z, E2.w};
        half8_t b[4];
        #pragma unroll
        for (int c = 0; c < 4; ++c)
            b[c] = *(const half8_t*)(fb + (size_t)w * 2048 + c * 512);

        #pragma unroll
        for (int t = 0; t < 4; ++t) {
            const unsigned bits = (mrow[t * (16*49) + w] >> (quad * 8)) & 0xffu;
            const short2v tt = __builtin_bit_cast(short2v, bits * 0x10001u);
            uint4_t af_u;
            #pragma unroll
            for (int p = 0; p < 4; ++p) {
                const short2v shl = (p == 0) ? (short2v){15,14} : (p == 1) ? (short2v){13,12}
                                 : (p == 2) ? (short2v){11,10} : (short2v){9,8};
                const short2v k = (tt << shl) >> (short2v){15,15};   // 0xFFFF/0x0000 per half
                const half2_t p1 = __builtin_bit_cast(half2_t, E1a[p]) * e1s[t];
                const half2_t p2 = __builtin_bit_cast(half2_t, E2a[p]) * e2s[t];
                const half2_t mx = __builtin_elementwise_max(p1, p2); // exp(lrelu) = max of exps
                const unsigned r = __builtin_bit_cast(unsigned, mx) & __builtin_bit_cast(unsigned, k);
                if (p == 0) af_u.x = r; else if (p == 1) af_u.y = r;
                else if (p == 2) af_u.z = r; else af_u.w = r;
            }
            const half8_t af = __builtin_bit_cast(half8_t, af_u);
            #pragma unroll
            for (int c = 0; c < 4; ++c)
                accN[t][c] = __builtin_amdgcn_mfma_f32_16x16x32_f16(af, b[c], accN[t][c], 0, 0, 0);
            accD[t] = __builtin_amdgcn_mfma_f32_16x16x32_f16(af, bones, accD[t], 0, 0, 0);
        }
    }

    const int slot = jc * N_HEADS + head;
    #pragma unroll
    for (int t = 0; t < 4; ++t) {
        if (m == 0) {
            #pragma unroll
            for (int r = 0; r < 4; ++r)
                pden[slot * N_NODES + rowbase + t * 16 + quad * 4 + r] = accD[t][r];
        }
        #pragma unroll
        for (int r = 0; r < 4; ++r) {
            const int gi = rowbase + t * 16 + quad * 4 + r;
            float* np_ = pnum + ((size_t)slot * N_NODES + gi) * N_HID + m;
            np_[0]  = accN[t][0][r];
            np_[16] = accN[t][1][r];
            np_[32] = accN[t][2][r];
            np_[48] = accN[t][3][r];
        }
    }
}

// ---------------- Kernel 3: reduce j-chunks, divide, mean over heads
__global__ __launch_bounds__(256) void finalize_kernel(
    const float* __restrict__ pnum, const float* __restrict__ pden,
    float* __restrict__ out, int js)
{
    const int idx = blockIdx.x * 256 + threadIdx.x;
    if (idx >= N_NODES * N_HID) return;
    const int i = idx >> 6;
    const int d = idx & 63;
    float s = 0.f;
    #pragma unroll
    for (int hh = 0; hh < N_HEADS; ++hh) {
        float ns = 0.f, ds = 0.f;
        for (int jc = 0; jc < js; ++jc) {
            const int slot = jc * N_HEADS + hh;
            ns += pnum[((size_t)slot * N_NODES + i) * N_HID + d];
            ds += pden[slot * N_NODES + i];
        }
        s += ns / ds;
    }
    out[idx] = 0.25f * s;
}

extern "C" void kernel_launch(void* const* d_in, const int* in_sizes, int n_in,
                              void* d_out, int out_size, void* d_ws, size_t ws_size,
                              hipStream_t stream)
{
    const float* h   = (const float*)d_in[0];
    const int*   adj = (const int*)d_in[1];
    const float* W   = (const float*)d_in[2];
    const float* a   = (const float*)d_in[3];
    float* out = (float*)d_out;

    char* ws = (char*)d_ws;
    short* htF = (short*)ws;
    size_t off = (size_t)N_HEADS * N_HID * N_NODES * 2;              // 3.1 MB
    float* srcv = (float*)(ws + off);        off += (size_t)N_HEADS * N_NODES * 4;
    unsigned* tE1pk = (unsigned*)(ws + off); off += (size_t)N_HEADS * (N_NODES/2) * 4;
    unsigned* tE2pk = (unsigned*)(ws + off); off += (size_t)N_HEADS * (N_NODES/2) * 4;
    unsigned* mask32 = (unsigned*)(ws + off); off += (size_t)N_NODES * NWORDS * 4;   // 4.7 MB

    const size_t per_js = (size_t)N_HEADS * N_NODES * N_HID * 4 + (size_t)N_HEADS * N_NODES * 4;
    int js = 8;
    if (off + 8 * per_js > ws_size) js = 4;   // fallback (R4 proved >=54.5MB fits; this is +2.7MB)
    const int nw = (N_NODES / js) / 32;       // 24 (js=8) or 48 (js=4)

    float* pnum = (float*)(ws + off);        off += (size_t)js * N_HEADS * N_NODES * N_HID * 4;
    float* pden = (float*)(ws + off);

    pack_adj_kernel<<<1536, 256, 0, stream>>>(adj, mask32);
    ht_gemm_kernel<<<dim3(N_NODES / 32, N_HEADS), 256, 0, stream>>>(h, W, a, htF, srcv, tE1pk, tE2pk);
    gat_main_kernel<<<dim3(N_NODES / 256, js, N_HEADS), dim3(64, 4), 0, stream>>>(
        mask32, htF, srcv, tE1pk, tE2pk, pnum, pden, nw);
    finalize_kernel<<<dim3((N_NODES * N_HID) / 256), 256, 0, stream>>>(pnum, pden, out, js);
}